// Round 2
// baseline (404.521 us; speedup 1.0000x reference)
//
#include <hip/hip_runtime.h>

// Butterfly multiply (untied), n=1024, 10 stages, increasing stride, + bias.
//
// R2: twiddles staged in LDS (80 KB, XOR-swizzled), shared by a 1024-thread
// persistent block. Each wave holds ROWS=4 rows in registers:
//   element e = i*256 + lane*4 + j  (i,j in 0..3) -> slot s = i*4 + j.
//   ls=0,1  : in-thread (j bits), float4 twiddle
//   ls=2..7 : cross-lane via __shfl_xor mask 1..32, float2 twiddle
//   ls=8,9  : in-thread (i bits), float4 twiddle
// LDS swizzle SW(f) = f ^ (((f>>5)&7)<<2): uniform bank use for every stage's
// read pattern; XORs only bits 2..4 so float2/float4 stay contiguous+aligned.

constexpr int ROWS   = 4;    // rows per wave
constexpr int WAVES  = 16;   // 1024 threads per block
constexpr int N      = 1024;
constexpr int TW_FLOATS = 10 * 2048;  // 20480 floats = 80 KB

__device__ __forceinline__ int SW(int f) {
    return f ^ (((f >> 5) & 7) << 2);
}

__device__ __forceinline__ void pair_update(float (&v)[ROWS][16], int s0, int s1,
                                            const float4 t4)
{
    #pragma unroll
    for (int r = 0; r < ROWS; ++r) {
        const float x0 = v[r][s0], x1 = v[r][s1];
        v[r][s0] = t4.x * x0 + t4.y * x1;
        v[r][s1] = t4.z * x0 + t4.w * x1;
    }
}

template<int LS>
__device__ __forceinline__ void cross_stage(float (&v)[ROWS][16],
                                            const float* __restrict__ tw_lds,
                                            int lane)
{
    constexpr int m = 1 << (LS - 2);              // lane xor mask
    const int ipos = (lane >> (LS - 2)) & 1;      // which half of the pair
    #pragma unroll
    for (int i = 0; i < 4; ++i) {
        #pragma unroll
        for (int j = 0; j < 4; ++j) {
            const int e    = i * 256 + lane * 4 + j;
            const int pair = ((e >> (LS + 1)) << LS) | (e & ((1 << LS) - 1));
            const int f    = LS * 2048 + pair * 4 + ipos * 2;
            const float2 t2 = *reinterpret_cast<const float2*>(&tw_lds[SW(f)]);
            const float ta = ipos ? t2.y : t2.x;  // coeff of own value
            const float tb = ipos ? t2.x : t2.y;  // coeff of partner value
            const int s = i * 4 + j;
            #pragma unroll
            for (int r = 0; r < ROWS; ++r) {
                const float own  = v[r][s];
                const float part = __shfl_xor(own, m, 64);
                v[r][s] = ta * own + tb * part;
            }
        }
    }
}

__global__ __launch_bounds__(WAVES * 64)
void butterfly_kernel(const float* __restrict__ x,
                      const float* __restrict__ tw,
                      const float* __restrict__ bias,
                      float* __restrict__ out,
                      int batch)
{
    __shared__ float tw_lds[TW_FLOATS];

    const int tid  = (int)threadIdx.x;
    const int lane = tid & 63;
    const int wave = tid >> 6;

    // ---- cooperative swizzled twiddle fill: 5120 float4s over 1024 threads
    #pragma unroll
    for (int k = 0; k < TW_FLOATS / (1024 * 4); ++k) {
        const int g = (k * 1024 + tid) * 4;
        const float4 t = *reinterpret_cast<const float4*>(tw + g);
        *reinterpret_cast<float4*>(&tw_lds[SW(g)]) = t;
    }

    // ---- bias into registers (reused every chunk)
    float4 b4[4];
    #pragma unroll
    for (int i = 0; i < 4; ++i)
        b4[i] = reinterpret_cast<const float4*>(bias)[i * 64 + lane];

    __syncthreads();

    const int rows_per_block = WAVES * ROWS;  // 64
    for (int base = (int)blockIdx.x * rows_per_block; base < batch;
         base += (int)gridDim.x * rows_per_block)
    {
        const int row0 = base + wave * ROWS;
        float v[ROWS][16];

        // ---- load: v[r][i*4+j] = x[row][i*256 + lane*4 + j]
        #pragma unroll
        for (int r = 0; r < ROWS; ++r) {
            const int row = (row0 + r < batch) ? (row0 + r) : (batch - 1);
            const float4* __restrict__ src =
                reinterpret_cast<const float4*>(x + (size_t)row * N);
            #pragma unroll
            for (int i = 0; i < 4; ++i) {
                const float4 t = src[i * 64 + lane];
                v[r][i*4+0] = t.x; v[r][i*4+1] = t.y;
                v[r][i*4+2] = t.z; v[r][i*4+3] = t.w;
            }
        }

        // ---- ls = 0 (stride 1): pair = i*128 + lane*2 + jj
        #pragma unroll
        for (int i = 0; i < 4; ++i) {
            #pragma unroll
            for (int jj = 0; jj < 2; ++jj) {
                const int f = (i * 128 + lane * 2 + jj) * 4;
                const float4 t4 = *reinterpret_cast<const float4*>(&tw_lds[SW(f)]);
                pair_update(v, i*4 + jj*2, i*4 + jj*2 + 1, t4);
            }
        }

        // ---- ls = 1 (stride 2): pair = i*128 + lane*2 + j
        #pragma unroll
        for (int i = 0; i < 4; ++i) {
            #pragma unroll
            for (int j = 0; j < 2; ++j) {
                const int f = 2048 + (i * 128 + lane * 2 + j) * 4;
                const float4 t4 = *reinterpret_cast<const float4*>(&tw_lds[SW(f)]);
                pair_update(v, i*4 + j, i*4 + j + 2, t4);
            }
        }

        // ---- ls = 2..7: cross-lane
        cross_stage<2>(v, tw_lds, lane);
        cross_stage<3>(v, tw_lds, lane);
        cross_stage<4>(v, tw_lds, lane);
        cross_stage<5>(v, tw_lds, lane);
        cross_stage<6>(v, tw_lds, lane);
        cross_stage<7>(v, tw_lds, lane);

        // ---- ls = 8 (stride 256): pair = ih*256 + lane*4 + j
        #pragma unroll
        for (int ih = 0; ih < 2; ++ih) {
            #pragma unroll
            for (int j = 0; j < 4; ++j) {
                const int f = 8 * 2048 + (ih * 256 + lane * 4 + j) * 4;
                const float4 t4 = *reinterpret_cast<const float4*>(&tw_lds[SW(f)]);
                pair_update(v, ih*8 + j, ih*8 + 4 + j, t4);
            }
        }

        // ---- ls = 9 (stride 512): pair = i*256 + lane*4 + j
        #pragma unroll
        for (int i = 0; i < 2; ++i) {
            #pragma unroll
            for (int j = 0; j < 4; ++j) {
                const int f = 9 * 2048 + (i * 256 + lane * 4 + j) * 4;
                const float4 t4 = *reinterpret_cast<const float4*>(&tw_lds[SW(f)]);
                pair_update(v, i*4 + j, i*4 + 8 + j, t4);
            }
        }

        // ---- bias + store (coalesced dwordx4)
        #pragma unroll
        for (int i = 0; i < 4; ++i) {
            #pragma unroll
            for (int r = 0; r < ROWS; ++r) {
                if (row0 + r < batch) {
                    float4 o;
                    o.x = v[r][i*4+0] + b4[i].x;
                    o.y = v[r][i*4+1] + b4[i].y;
                    o.z = v[r][i*4+2] + b4[i].z;
                    o.w = v[r][i*4+3] + b4[i].w;
                    *reinterpret_cast<float4*>(
                        out + (size_t)(row0 + r) * N + i * 256 + lane * 4) = o;
                }
            }
        }
    }
}

extern "C" void kernel_launch(void* const* d_in, const int* in_sizes, int n_in,
                              void* d_out, int out_size, void* d_ws, size_t ws_size,
                              hipStream_t stream)
{
    (void)n_in; (void)d_ws; (void)ws_size; (void)out_size;
    const float* x    = (const float*)d_in[0];
    const float* tw   = (const float*)d_in[1];
    const float* bias = (const float*)d_in[2];
    float* out        = (float*)d_out;

    const int batch = in_sizes[0] / N;
    const int rows_per_block = WAVES * ROWS * 1;  // 64 rows per block-iteration
    int blocks = (batch + rows_per_block - 1) / rows_per_block;
    if (blocks > 256) blocks = 256;               // persistent, 1 block/CU
    if (blocks < 1) blocks = 1;
    hipLaunchKernelGGL(butterfly_kernel, dim3(blocks), dim3(WAVES * 64), 0, stream,
                       x, tw, bias, out, batch);
}

// Round 3
// 323.013 us; speedup vs baseline: 1.2523x; 1.2523x over previous
//
#include <hip/hip_runtime.h>

// Butterfly multiply (untied), n=1024, 10 stages, increasing stride, + bias.
//
// R3: 256-thread blocks (4 waves), ROWS=8 rows per wave, twiddles staged in
// 80 KB LDS (XOR-swizzled, 2x2 stored pre-swapped), persistent grid.
//
// Layout: element e = i*256 + lane*4 + j (i,j in 0..3) -> slot s = i*4+j.
//   ls=0,1  : in-thread (j bits), float4 twiddle
//   ls=2..7 : cross-lane via __shfl_xor mask 1..32, float2 twiddle
//   ls=8,9  : in-thread (i bits), float4 twiddle
// LDS swizzle SW(f) = f ^ (((f>>5)&7)<<2): XORs only bits 2..4 of the float
// index, so float2/float4 stay contiguous and aligned.
// Each 2x2 (a,b,c,d) is stored as (a,b,d,c): cross-stage lanes then read
// [coeff_of_own, coeff_of_partner] directly at pair*4 + ipos*2 (no selects);
// in-thread stages use y0 = x*v0 + y*v1, y1 = w*v0 + z*v1.

constexpr int ROWS  = 8;    // rows per wave
constexpr int WAVES = 4;    // 256 threads per block
constexpr int N     = 1024;
constexpr int TW_FLOATS = 10 * 2048;  // 20480 floats = 80 KB

__device__ __forceinline__ int SW(int f) {
    return f ^ (((f >> 5) & 7) << 2);
}

// swapped-storage 2x2: t4 = (t00, t01, t11, t10)
__device__ __forceinline__ void pair_update(float (&v)[ROWS][16], int s0, int s1,
                                            const float4 t4)
{
    #pragma unroll
    for (int r = 0; r < ROWS; ++r) {
        const float x0 = v[r][s0], x1 = v[r][s1];
        v[r][s0] = t4.x * x0 + t4.y * x1;
        v[r][s1] = t4.w * x0 + t4.z * x1;
    }
}

template<int LS>
__device__ __forceinline__ void cross_stage(float (&v)[ROWS][16],
                                            const float* __restrict__ tw_lds,
                                            int lane)
{
    constexpr int m = 1 << (LS - 2);              // lane xor mask
    const int ipos = (lane >> (LS - 2)) & 1;      // which half of the pair
    #pragma unroll
    for (int i = 0; i < 4; ++i) {
        #pragma unroll
        for (int j = 0; j < 4; ++j) {
            const int e    = i * 256 + lane * 4 + j;
            const int pair = ((e >> (LS + 1)) << LS) | (e & ((1 << LS) - 1));
            const int f    = LS * 2048 + pair * 4 + ipos * 2;
            const float2 t2 = *reinterpret_cast<const float2*>(&tw_lds[SW(f)]);
            const int s = i * 4 + j;
            #pragma unroll
            for (int r = 0; r < ROWS; ++r) {
                const float own  = v[r][s];
                const float part = __shfl_xor(own, m, 64);
                v[r][s] = t2.x * own + t2.y * part;
            }
        }
    }
}

__global__ __launch_bounds__(WAVES * 64, 2)
void butterfly_kernel(const float* __restrict__ x,
                      const float* __restrict__ tw,
                      const float* __restrict__ bias,
                      float* __restrict__ out,
                      int batch)
{
    __shared__ float tw_lds[TW_FLOATS];

    const int tid  = (int)threadIdx.x;
    const int lane = tid & 63;
    const int wave = tid >> 6;

    // ---- cooperative swizzled twiddle fill (one float4 == one 2x2; swap z/w)
    #pragma unroll
    for (int k = 0; k < TW_FLOATS / (256 * 4); ++k) {
        const int g = (k * 256 + tid) * 4;
        const float4 t = *reinterpret_cast<const float4*>(tw + g);
        float4 s;
        s.x = t.x; s.y = t.y; s.z = t.w; s.w = t.z;
        *reinterpret_cast<float4*>(&tw_lds[SW(g)]) = s;
    }

    // ---- bias into registers (reused every chunk)
    float4 b4[4];
    #pragma unroll
    for (int i = 0; i < 4; ++i)
        b4[i] = reinterpret_cast<const float4*>(bias)[i * 64 + lane];

    __syncthreads();

    const int rows_per_iter = WAVES * ROWS;  // 32
    for (int base = (int)blockIdx.x * rows_per_iter; base < batch;
         base += (int)gridDim.x * rows_per_iter)
    {
        const int row0 = base + wave * ROWS;
        float v[ROWS][16];

        // ---- load: v[r][i*4+j] = x[row][i*256 + lane*4 + j] (dwordx4)
        #pragma unroll
        for (int r = 0; r < ROWS; ++r) {
            const int row = (row0 + r < batch) ? (row0 + r) : (batch - 1);
            const float4* __restrict__ src =
                reinterpret_cast<const float4*>(x + (size_t)row * N);
            #pragma unroll
            for (int i = 0; i < 4; ++i) {
                const float4 t = src[i * 64 + lane];
                v[r][i*4+0] = t.x; v[r][i*4+1] = t.y;
                v[r][i*4+2] = t.z; v[r][i*4+3] = t.w;
            }
        }

        // ---- ls = 0 (stride 1): pair = i*128 + lane*2 + jj
        #pragma unroll
        for (int i = 0; i < 4; ++i) {
            #pragma unroll
            for (int jj = 0; jj < 2; ++jj) {
                const int f = (i * 128 + lane * 2 + jj) * 4;
                const float4 t4 = *reinterpret_cast<const float4*>(&tw_lds[SW(f)]);
                pair_update(v, i*4 + jj*2, i*4 + jj*2 + 1, t4);
            }
        }

        // ---- ls = 1 (stride 2): pair = i*128 + lane*2 + j
        #pragma unroll
        for (int i = 0; i < 4; ++i) {
            #pragma unroll
            for (int j = 0; j < 2; ++j) {
                const int f = 2048 + (i * 128 + lane * 2 + j) * 4;
                const float4 t4 = *reinterpret_cast<const float4*>(&tw_lds[SW(f)]);
                pair_update(v, i*4 + j, i*4 + j + 2, t4);
            }
        }

        // ---- ls = 2..7: cross-lane
        cross_stage<2>(v, tw_lds, lane);
        cross_stage<3>(v, tw_lds, lane);
        cross_stage<4>(v, tw_lds, lane);
        cross_stage<5>(v, tw_lds, lane);
        cross_stage<6>(v, tw_lds, lane);
        cross_stage<7>(v, tw_lds, lane);

        // ---- ls = 8 (stride 256): pair = ih*256 + lane*4 + j
        #pragma unroll
        for (int ih = 0; ih < 2; ++ih) {
            #pragma unroll
            for (int j = 0; j < 4; ++j) {
                const int f = 8 * 2048 + (ih * 256 + lane * 4 + j) * 4;
                const float4 t4 = *reinterpret_cast<const float4*>(&tw_lds[SW(f)]);
                pair_update(v, ih*8 + j, ih*8 + 4 + j, t4);
            }
        }

        // ---- ls = 9 (stride 512): pair = i*256 + lane*4 + j
        #pragma unroll
        for (int i = 0; i < 2; ++i) {
            #pragma unroll
            for (int j = 0; j < 4; ++j) {
                const int f = 9 * 2048 + (i * 256 + lane * 4 + j) * 4;
                const float4 t4 = *reinterpret_cast<const float4*>(&tw_lds[SW(f)]);
                pair_update(v, i*4 + j, i*4 + 8 + j, t4);
            }
        }

        // ---- bias + store (coalesced dwordx4)
        #pragma unroll
        for (int i = 0; i < 4; ++i) {
            #pragma unroll
            for (int r = 0; r < ROWS; ++r) {
                if (row0 + r < batch) {
                    float4 o;
                    o.x = v[r][i*4+0] + b4[i].x;
                    o.y = v[r][i*4+1] + b4[i].y;
                    o.z = v[r][i*4+2] + b4[i].z;
                    o.w = v[r][i*4+3] + b4[i].w;
                    *reinterpret_cast<float4*>(
                        out + (size_t)(row0 + r) * N + i * 256 + lane * 4) = o;
                }
            }
        }
    }
}

extern "C" void kernel_launch(void* const* d_in, const int* in_sizes, int n_in,
                              void* d_out, int out_size, void* d_ws, size_t ws_size,
                              hipStream_t stream)
{
    (void)n_in; (void)d_ws; (void)ws_size; (void)out_size;
    const float* x    = (const float*)d_in[0];
    const float* tw   = (const float*)d_in[1];
    const float* bias = (const float*)d_in[2];
    float* out        = (float*)d_out;

    const int batch = in_sizes[0] / N;
    const int rows_per_iter = WAVES * ROWS;  // 32
    int blocks = (batch + rows_per_iter - 1) / rows_per_iter;
    if (blocks > 512) blocks = 512;          // persistent, 2 blocks/CU
    if (blocks < 1) blocks = 1;
    hipLaunchKernelGGL(butterfly_kernel, dim3(blocks), dim3(WAVES * 64), 0, stream,
                       x, tw, bias, out, batch);
}

// Round 4
// 153.247 us; speedup vs baseline: 2.6397x; 2.1078x over previous
//
#include <hip/hip_runtime.h>

// Butterfly multiply (untied), n=1024, 10 stages, increasing stride, + bias.
//
// R4: R3 structure (256-thread blocks, ROWS=8 per wave, 80 KB swizzled LDS
// twiddles, persistent grid) with the register cap fixed: no __launch_bounds__
// second arg (it forced VGPR<=128 -> spill in R2/R3). Instead:
//   amdgpu_flat_work_group_size(256,256)  - exact block size
//   amdgpu_waves_per_eu(1,2)              - min 1 wave/EU -> VGPR cap 512,
//                                           allocator takes the ~200 it needs.
// Occupancy is LDS-bound regardless: 80 KB -> 2 blocks/CU = 8 waves/CU.
//
// Layout: element e = i*256 + lane*4 + j (i,j in 0..3) -> slot s = i*4+j.
//   ls=0,1  : in-thread (j bits), float4 twiddle
//   ls=2..7 : cross-lane via __shfl_xor mask 1..32, float2 twiddle
//   ls=8,9  : in-thread (i bits), float4 twiddle
// LDS swizzle SW(f) = f ^ (((f>>5)&7)<<2): XORs only bits 2..4 of the float
// index -> float2/float4 contiguity and alignment preserved, banks spread.
// Each 2x2 (a,b,c,d) stored pre-swapped as (a,b,d,c): cross-stage lanes read
// [coeff_of_own, coeff_of_partner] directly; in-thread stages use w/z.

constexpr int ROWS  = 8;    // rows per wave
constexpr int WAVES = 4;    // 256 threads per block
constexpr int N     = 1024;
constexpr int TW_FLOATS = 10 * 2048;  // 20480 floats = 80 KB

__device__ __forceinline__ int SW(int f) {
    return f ^ (((f >> 5) & 7) << 2);
}

// swapped-storage 2x2: t4 = (t00, t01, t11, t10)
__device__ __forceinline__ void pair_update(float (&v)[ROWS][16], int s0, int s1,
                                            const float4 t4)
{
    #pragma unroll
    for (int r = 0; r < ROWS; ++r) {
        const float x0 = v[r][s0], x1 = v[r][s1];
        v[r][s0] = t4.x * x0 + t4.y * x1;
        v[r][s1] = t4.w * x0 + t4.z * x1;
    }
}

template<int LS>
__device__ __forceinline__ void cross_stage(float (&v)[ROWS][16],
                                            const float* __restrict__ tw_lds,
                                            int lane)
{
    constexpr int m = 1 << (LS - 2);              // lane xor mask
    const int ipos = (lane >> (LS - 2)) & 1;      // which half of the pair
    #pragma unroll
    for (int i = 0; i < 4; ++i) {
        #pragma unroll
        for (int j = 0; j < 4; ++j) {
            const int e    = i * 256 + lane * 4 + j;
            const int pair = ((e >> (LS + 1)) << LS) | (e & ((1 << LS) - 1));
            const int f    = LS * 2048 + pair * 4 + ipos * 2;
            const float2 t2 = *reinterpret_cast<const float2*>(&tw_lds[SW(f)]);
            const int s = i * 4 + j;
            #pragma unroll
            for (int r = 0; r < ROWS; ++r) {
                const float own  = v[r][s];
                const float part = __shfl_xor(own, m, 64);
                v[r][s] = t2.x * own + t2.y * part;
            }
        }
    }
}

__global__ __attribute__((amdgpu_flat_work_group_size(256, 256),
                          amdgpu_waves_per_eu(1, 2)))
void butterfly_kernel(const float* __restrict__ x,
                      const float* __restrict__ tw,
                      const float* __restrict__ bias,
                      float* __restrict__ out,
                      int batch)
{
    __shared__ float tw_lds[TW_FLOATS];

    const int tid  = (int)threadIdx.x;
    const int lane = tid & 63;
    const int wave = tid >> 6;

    // ---- cooperative swizzled twiddle fill (one float4 == one 2x2; swap z/w)
    #pragma unroll
    for (int k = 0; k < TW_FLOATS / (256 * 4); ++k) {
        const int g = (k * 256 + tid) * 4;
        const float4 t = *reinterpret_cast<const float4*>(tw + g);
        float4 s;
        s.x = t.x; s.y = t.y; s.z = t.w; s.w = t.z;
        *reinterpret_cast<float4*>(&tw_lds[SW(g)]) = s;
    }

    // ---- bias into registers (reused every chunk)
    float4 b4[4];
    #pragma unroll
    for (int i = 0; i < 4; ++i)
        b4[i] = reinterpret_cast<const float4*>(bias)[i * 64 + lane];

    __syncthreads();

    const int rows_per_iter = WAVES * ROWS;  // 32
    for (int base = (int)blockIdx.x * rows_per_iter; base < batch;
         base += (int)gridDim.x * rows_per_iter)
    {
        const int row0 = base + wave * ROWS;
        float v[ROWS][16];

        // ---- load: v[r][i*4+j] = x[row][i*256 + lane*4 + j] (dwordx4)
        #pragma unroll
        for (int r = 0; r < ROWS; ++r) {
            const int row = (row0 + r < batch) ? (row0 + r) : (batch - 1);
            const float4* __restrict__ src =
                reinterpret_cast<const float4*>(x + (size_t)row * N);
            #pragma unroll
            for (int i = 0; i < 4; ++i) {
                const float4 t = src[i * 64 + lane];
                v[r][i*4+0] = t.x; v[r][i*4+1] = t.y;
                v[r][i*4+2] = t.z; v[r][i*4+3] = t.w;
            }
        }

        // ---- ls = 0 (stride 1): pair = i*128 + lane*2 + jj
        #pragma unroll
        for (int i = 0; i < 4; ++i) {
            #pragma unroll
            for (int jj = 0; jj < 2; ++jj) {
                const int f = (i * 128 + lane * 2 + jj) * 4;
                const float4 t4 = *reinterpret_cast<const float4*>(&tw_lds[SW(f)]);
                pair_update(v, i*4 + jj*2, i*4 + jj*2 + 1, t4);
            }
        }

        // ---- ls = 1 (stride 2): pair = i*128 + lane*2 + j
        #pragma unroll
        for (int i = 0; i < 4; ++i) {
            #pragma unroll
            for (int j = 0; j < 2; ++j) {
                const int f = 2048 + (i * 128 + lane * 2 + j) * 4;
                const float4 t4 = *reinterpret_cast<const float4*>(&tw_lds[SW(f)]);
                pair_update(v, i*4 + j, i*4 + j + 2, t4);
            }
        }

        // ---- ls = 2..7: cross-lane
        cross_stage<2>(v, tw_lds, lane);
        cross_stage<3>(v, tw_lds, lane);
        cross_stage<4>(v, tw_lds, lane);
        cross_stage<5>(v, tw_lds, lane);
        cross_stage<6>(v, tw_lds, lane);
        cross_stage<7>(v, tw_lds, lane);

        // ---- ls = 8 (stride 256): pair = ih*256 + lane*4 + j
        #pragma unroll
        for (int ih = 0; ih < 2; ++ih) {
            #pragma unroll
            for (int j = 0; j < 4; ++j) {
                const int f = 8 * 2048 + (ih * 256 + lane * 4 + j) * 4;
                const float4 t4 = *reinterpret_cast<const float4*>(&tw_lds[SW(f)]);
                pair_update(v, ih*8 + j, ih*8 + 4 + j, t4);
            }
        }

        // ---- ls = 9 (stride 512): pair = i*256 + lane*4 + j
        #pragma unroll
        for (int i = 0; i < 2; ++i) {
            #pragma unroll
            for (int j = 0; j < 4; ++j) {
                const int f = 9 * 2048 + (i * 256 + lane * 4 + j) * 4;
                const float4 t4 = *reinterpret_cast<const float4*>(&tw_lds[SW(f)]);
                pair_update(v, i*4 + j, i*4 + 8 + j, t4);
            }
        }

        // ---- bias + store (coalesced dwordx4)
        #pragma unroll
        for (int i = 0; i < 4; ++i) {
            #pragma unroll
            for (int r = 0; r < ROWS; ++r) {
                if (row0 + r < batch) {
                    float4 o;
                    o.x = v[r][i*4+0] + b4[i].x;
                    o.y = v[r][i*4+1] + b4[i].y;
                    o.z = v[r][i*4+2] + b4[i].z;
                    o.w = v[r][i*4+3] + b4[i].w;
                    *reinterpret_cast<float4*>(
                        out + (size_t)(row0 + r) * N + i * 256 + lane * 4) = o;
                }
            }
        }
    }
}

extern "C" void kernel_launch(void* const* d_in, const int* in_sizes, int n_in,
                              void* d_out, int out_size, void* d_ws, size_t ws_size,
                              hipStream_t stream)
{
    (void)n_in; (void)d_ws; (void)ws_size; (void)out_size;
    const float* x    = (const float*)d_in[0];
    const float* tw   = (const float*)d_in[1];
    const float* bias = (const float*)d_in[2];
    float* out        = (float*)d_out;

    const int batch = in_sizes[0] / N;
    const int rows_per_iter = WAVES * ROWS;  // 32
    int blocks = (batch + rows_per_iter - 1) / rows_per_iter;
    if (blocks > 512) blocks = 512;          // persistent, 2 blocks/CU
    if (blocks < 1) blocks = 1;
    hipLaunchKernelGGL(butterfly_kernel, dim3(blocks), dim3(WAVES * 64), 0, stream,
                       x, tw, bias, out, batch);
}